// Round 4
// baseline (246.446 us; speedup 1.0000x reference)
//
#include <hip/hip_runtime.h>
#include <math.h>

#define NH 12
#define DMODEL 768
#define DHEAD 64
#define BATCH 16
#define SEQ 512
#define NTOK (BATCH*SEQ)   // 8192
#define ATTN_SCALE 0.125f
#define LN_EPS 1e-3f
#define PADB 72            // padded LDS row length (bf16) for 64-wide tiles
#define KITERS (DMODEL/32) // 24

typedef __attribute__((ext_vector_type(8))) short  bf16x8;
typedef __attribute__((ext_vector_type(8))) unsigned short ushort8;
typedef __attribute__((ext_vector_type(4))) float  f32x4;

__device__ __forceinline__ unsigned short f2bf(float f) {
    unsigned int u = __float_as_uint(f);
    unsigned int r = (u + 0x7fffu + ((u >> 16) & 1u)) >> 16;
    return (unsigned short)r;
}
__device__ __forceinline__ float bf2f(unsigned short h) {
    return __uint_as_float(((unsigned int)h) << 16);
}

__device__ __forceinline__ void async_copy16(const void* g, void* l) {
    __builtin_amdgcn_global_load_lds((const __attribute__((address_space(1))) void*)g,
                                     (__attribute__((address_space(3))) void*)l,
                                     16, 0, 0);
}

// ---------------------------------------------------------------------------
// Prep 1: cast x (fp32) -> xb (bf16), same [NTOK][DMODEL] layout.
// ---------------------------------------------------------------------------
__global__ __launch_bounds__(256) void cast_x_kernel(
    const float* __restrict__ x, unsigned short* __restrict__ xb)
{
    int i = (blockIdx.x * 256 + threadIdx.x) * 4;
    const float4 v = *(const float4*)(x + i);
    unsigned short o0 = f2bf(v.x), o1 = f2bf(v.y), o2 = f2bf(v.z), o3 = f2bf(v.w);
    unsigned long long pack = (unsigned long long)o0 | ((unsigned long long)o1 << 16)
                            | ((unsigned long long)o2 << 32) | ((unsigned long long)o3 << 48);
    *(unsigned long long*)(xb + i) = pack;
}

// ---------------------------------------------------------------------------
// Prep 2: Wt[n][k] = bf16(W[k][n]) for all 4 weight matrices (z index).
// ---------------------------------------------------------------------------
__global__ __launch_bounds__(256) void prep_wt_kernel(
    const float* __restrict__ Wq, const float* __restrict__ Wk,
    const float* __restrict__ Wv, const float* __restrict__ Wo,
    unsigned short* __restrict__ tq, unsigned short* __restrict__ tk,
    unsigned short* __restrict__ tv, unsigned short* __restrict__ to_)
{
    const int zz = blockIdx.z;
    const float* W = (zz == 0) ? Wq : (zz == 1) ? Wk : (zz == 2) ? Wv : Wo;
    unsigned short* T = (zz == 0) ? tq : (zz == 1) ? tk : (zz == 2) ? tv : to_;

    __shared__ float tile[32][33];
    const int bx = blockIdx.x * 32;   // k base
    const int by = blockIdx.y * 32;   // n base
    const int tx = threadIdx.x & 31, ty = threadIdx.x >> 5;   // ty 0..7

    #pragma unroll
    for (int i = 0; i < 32; i += 8)
        tile[ty + i][tx] = W[(size_t)(bx + ty + i) * DMODEL + by + tx];
    __syncthreads();
    #pragma unroll
    for (int i = 0; i < 32; i += 8)
        T[(size_t)(by + ty + i) * DMODEL + bx + tx] = f2bf(tile[tx][ty + i]);
}

// ---------------------------------------------------------------------------
// MFMA GEMM, double-buffered K-loop (one barrier per iter; prefetch issued
// AFTER the barrier so the vmcnt(0) drain at the next barrier comes a full
// compute phase later). 128x128 tile, BK=32, 4 waves in 2x2.
// QKV variant: bias add; Q,K scatter to [B,H,L,DH]; V scatter TRANSPOSED to
// [B,H,DH,SEQ] (packed 8B stores) so attention's PV B-frags are contiguous.
// ---------------------------------------------------------------------------
__global__ __launch_bounds__(256) void mfma_gemm_qkv(
    const unsigned short* __restrict__ xb,
    const unsigned short* __restrict__ wt0, const unsigned short* __restrict__ wt1,
    const unsigned short* __restrict__ wt2,
    const float* __restrict__ b0, const float* __restrict__ b1, const float* __restrict__ b2,
    unsigned short* __restrict__ o0, unsigned short* __restrict__ o1,
    unsigned short* __restrict__ o2)
{
    __shared__ __align__(16) unsigned short As[2][128 * 32];
    __shared__ __align__(16) unsigned short Bs[2][128 * 32];

    const int zz = blockIdx.z;
    const unsigned short* Wt = (zz == 0) ? wt0 : (zz == 1) ? wt1 : wt2;
    const float* bias        = (zz == 0) ? b0  : (zz == 1) ? b1  : b2;
    unsigned short* out      = (zz == 0) ? o0  : (zz == 1) ? o1  : o2;

    const int tid  = threadIdx.x;
    const int lane = tid & 63;
    const int w    = tid >> 6;
    const int wm   = w >> 1, wn = w & 1;
    const int m0   = blockIdx.x * 128;
    const int n0   = blockIdx.y * 128;
    const int quad = lane >> 4;
    const int l16  = lane & 15;

    const int row0 = (2 * w)     * 16 + (lane >> 2);
    const int row1 = (2 * w + 1) * 16 + (lane >> 2);
    const int koff = (lane & 3) * 8;

    f32x4 acc[4][4] = {};

    // prologue: stage k-tile 0 into buffer 0
    {
        const int k0 = 0;
        async_copy16(xb + (size_t)(m0 + row0) * DMODEL + k0 + koff, &As[0][(2 * w)     * 512]);
        async_copy16(xb + (size_t)(m0 + row1) * DMODEL + k0 + koff, &As[0][(2 * w + 1) * 512]);
        async_copy16(Wt + (size_t)(n0 + row0) * DMODEL + k0 + koff, &Bs[0][(2 * w)     * 512]);
        async_copy16(Wt + (size_t)(n0 + row1) * DMODEL + k0 + koff, &Bs[0][(2 * w + 1) * 512]);
    }

    for (int kb = 0; kb < KITERS; ++kb) {
        __syncthreads();   // buf[kb&1] loads landed; prior iter's ds_reads drained
        if (kb + 1 < KITERS) {
            const int k0 = (kb + 1) * 32;
            const int nb = (kb + 1) & 1;
            async_copy16(xb + (size_t)(m0 + row0) * DMODEL + k0 + koff, &As[nb][(2 * w)     * 512]);
            async_copy16(xb + (size_t)(m0 + row1) * DMODEL + k0 + koff, &As[nb][(2 * w + 1) * 512]);
            async_copy16(Wt + (size_t)(n0 + row0) * DMODEL + k0 + koff, &Bs[nb][(2 * w)     * 512]);
            async_copy16(Wt + (size_t)(n0 + row1) * DMODEL + k0 + koff, &Bs[nb][(2 * w + 1) * 512]);
        }
        const unsigned short* A = As[kb & 1];
        const unsigned short* B = Bs[kb & 1];

        bf16x8 a[4], b[4];
        #pragma unroll
        for (int mi = 0; mi < 4; ++mi)
            a[mi] = *(const bf16x8*)&A[(wm * 64 + mi * 16 + l16) * 32 + quad * 8];
        #pragma unroll
        for (int ni = 0; ni < 4; ++ni)
            b[ni] = *(const bf16x8*)&B[(wn * 64 + ni * 16 + l16) * 32 + quad * 8];
        #pragma unroll
        for (int mi = 0; mi < 4; ++mi)
            #pragma unroll
            for (int ni = 0; ni < 4; ++ni)
                acc[mi][ni] = __builtin_amdgcn_mfma_f32_16x16x32_bf16(a[mi], b[ni], acc[mi][ni], 0, 0, 0);
    }

    if (zz == 2) {
        // V: write transposed [B,H,DH,SEQ]; 4 consecutive tokens pack to 8B.
        #pragma unroll
        for (int ni = 0; ni < 4; ++ni) {
            const int ncol = n0 + wn * 64 + ni * 16 + l16;
            const int h = ncol >> 6, dh = ncol & 63;
            const float bv = bias[ncol];
            #pragma unroll
            for (int mi = 0; mi < 4; ++mi) {
                const int mbase = m0 + wm * 64 + mi * 16 + quad * 4;
                const int bi = mbase >> 9, l = mbase & 511;
                unsigned long long pack = 0;
                #pragma unroll
                for (int r = 0; r < 4; ++r)
                    pack |= (unsigned long long)f2bf(acc[mi][ni][r] + bv) << (16 * r);
                *(unsigned long long*)(out + ((size_t)((bi * NH + h) * DHEAD + dh)) * SEQ + l) = pack;
            }
        }
    } else {
        #pragma unroll
        for (int ni = 0; ni < 4; ++ni) {
            const int ncol = n0 + wn * 64 + ni * 16 + l16;
            const int h = ncol >> 6, dh = ncol & 63;
            const float bv = bias[ncol];
            #pragma unroll
            for (int mi = 0; mi < 4; ++mi) {
                const int mbase = m0 + wm * 64 + mi * 16 + quad * 4;
                #pragma unroll
                for (int r = 0; r < 4; ++r) {
                    const int t = mbase + r;
                    const int bi = t >> 9, l = t & 511;
                    out[(size_t)((bi * NH + h) * SEQ + l) * DHEAD + dh] = f2bf(acc[mi][ni][r] + bv);
                }
            }
        }
    }
}

// O-proj variant: y = ctx @ Wo + bo + x (fp32 out), same dbuf K-loop.
__global__ __launch_bounds__(256) void mfma_gemm_oproj(
    const unsigned short* __restrict__ ctxb, const unsigned short* __restrict__ wto,
    const float* __restrict__ bo, const float* __restrict__ x,
    float* __restrict__ y)
{
    __shared__ __align__(16) unsigned short As[2][128 * 32];
    __shared__ __align__(16) unsigned short Bs[2][128 * 32];

    const int tid  = threadIdx.x;
    const int lane = tid & 63;
    const int w    = tid >> 6;
    const int wm   = w >> 1, wn = w & 1;
    const int m0   = blockIdx.x * 128;
    const int n0   = blockIdx.y * 128;
    const int quad = lane >> 4;
    const int l16  = lane & 15;

    const int row0 = (2 * w)     * 16 + (lane >> 2);
    const int row1 = (2 * w + 1) * 16 + (lane >> 2);
    const int koff = (lane & 3) * 8;

    f32x4 acc[4][4] = {};

    {
        const int k0 = 0;
        async_copy16(ctxb + (size_t)(m0 + row0) * DMODEL + k0 + koff, &As[0][(2 * w)     * 512]);
        async_copy16(ctxb + (size_t)(m0 + row1) * DMODEL + k0 + koff, &As[0][(2 * w + 1) * 512]);
        async_copy16(wto  + (size_t)(n0 + row0) * DMODEL + k0 + koff, &Bs[0][(2 * w)     * 512]);
        async_copy16(wto  + (size_t)(n0 + row1) * DMODEL + k0 + koff, &Bs[0][(2 * w + 1) * 512]);
    }

    for (int kb = 0; kb < KITERS; ++kb) {
        __syncthreads();
        if (kb + 1 < KITERS) {
            const int k0 = (kb + 1) * 32;
            const int nb = (kb + 1) & 1;
            async_copy16(ctxb + (size_t)(m0 + row0) * DMODEL + k0 + koff, &As[nb][(2 * w)     * 512]);
            async_copy16(ctxb + (size_t)(m0 + row1) * DMODEL + k0 + koff, &As[nb][(2 * w + 1) * 512]);
            async_copy16(wto  + (size_t)(n0 + row0) * DMODEL + k0 + koff, &Bs[nb][(2 * w)     * 512]);
            async_copy16(wto  + (size_t)(n0 + row1) * DMODEL + k0 + koff, &Bs[nb][(2 * w + 1) * 512]);
        }
        const unsigned short* A = As[kb & 1];
        const unsigned short* B = Bs[kb & 1];

        bf16x8 a[4], b[4];
        #pragma unroll
        for (int mi = 0; mi < 4; ++mi)
            a[mi] = *(const bf16x8*)&A[(wm * 64 + mi * 16 + l16) * 32 + quad * 8];
        #pragma unroll
        for (int ni = 0; ni < 4; ++ni)
            b[ni] = *(const bf16x8*)&B[(wn * 64 + ni * 16 + l16) * 32 + quad * 8];
        #pragma unroll
        for (int mi = 0; mi < 4; ++mi)
            #pragma unroll
            for (int ni = 0; ni < 4; ++ni)
                acc[mi][ni] = __builtin_amdgcn_mfma_f32_16x16x32_bf16(a[mi], b[ni], acc[mi][ni], 0, 0, 0);
    }

    #pragma unroll
    for (int ni = 0; ni < 4; ++ni) {
        const int ncol = n0 + wn * 64 + ni * 16 + l16;
        const float bv = bo[ncol];
        #pragma unroll
        for (int mi = 0; mi < 4; ++mi) {
            const int mbase = m0 + wm * 64 + mi * 16 + quad * 4;
            #pragma unroll
            for (int r = 0; r < 4; ++r) {
                const size_t idx = (size_t)(mbase + r) * DMODEL + ncol;
                y[idx] = acc[mi][ni][r] + bv + x[idx];
            }
        }
    }
}

// ---------------------------------------------------------------------------
// MFMA flash attention. Block = (b, h, 128-query tile); 4 waves x 32 q-rows.
// K-tiles of 64. S=Q·K^T via mfma; P -> LDS round-trip (C-layout -> A-layout);
// row sums via ones-MFMA; V pre-transposed globally to [B,H,DH,SEQ].
// ---------------------------------------------------------------------------
__global__ __launch_bounds__(256) void attn_mfma_kernel(
    const unsigned short* __restrict__ q, const unsigned short* __restrict__ k,
    const unsigned short* __restrict__ vt, const int* __restrict__ mask,
    unsigned short* __restrict__ ctxb)
{
    __shared__ __align__(16) unsigned short Ks[64 * PADB];
    __shared__ __align__(16) unsigned short Vs[64 * PADB];   // V^T tile: [d][key]
    __shared__ __align__(16) unsigned short QP[128 * PADB];  // Q staging, then P
    __shared__ float maskF[64];

    const int tid  = threadIdx.x;
    const int lane = tid & 63;
    const int w    = tid >> 6;
    const int quad = lane >> 4;
    const int l16  = lane & 15;
    const int q0   = blockIdx.x * 128;
    const int h    = blockIdx.y;
    const int b    = blockIdx.z;

    const unsigned short* qp  = q  + ((size_t)(b * NH + h) * SEQ + q0) * DHEAD;
    const unsigned short* kp  = k  + (size_t)(b * NH + h) * SEQ * DHEAD;
    const unsigned short* vtp = vt + (size_t)(b * NH + h) * DHEAD * SEQ;

    // stage Q tile (128x64) into QP
    #pragma unroll
    for (int i = 0; i < 4; ++i) {
        int idx = tid * 8 + 2048 * i;
        *(ushort8*)&QP[(idx >> 6) * PADB + (idx & 63)] = *(const ushort8*)(qp + idx);
    }
    __syncthreads();

    bf16x8 aQ[2][2];
    #pragma unroll
    for (int mi = 0; mi < 2; ++mi)
        #pragma unroll
        for (int kb = 0; kb < 2; ++kb)
            aQ[mi][kb] = *(const bf16x8*)&QP[(w * 32 + mi * 16 + l16) * PADB + kb * 32 + quad * 8];

    bf16x8 ones;
    #pragma unroll
    for (int j = 0; j < 8; ++j) ones[j] = (short)0x3F80;   // bf16 1.0

    float m_st[2][4], l_st[2][4];
    #pragma unroll
    for (int mi = 0; mi < 2; ++mi)
        #pragma unroll
        for (int r = 0; r < 4; ++r) { m_st[mi][r] = -1e30f; l_st[mi][r] = 0.f; }
    f32x4 o[2][4] = {};
    const f32x4 zf = {0.f, 0.f, 0.f, 0.f};

    for (int kt = 0; kt < SEQ; kt += 64) {
        __syncthreads();   // prior iter's Ks/Vs reads (and first-iter aQ) done
        #pragma unroll
        for (int i = 0; i < 2; ++i) {
            int idx = tid * 8 + 2048 * i;
            int r = idx >> 6, c = idx & 63;
            *(ushort8*)&Ks[r * PADB + c] = *(const ushort8*)(kp + (size_t)kt * DHEAD + idx);
            *(ushort8*)&Vs[r * PADB + c] = *(const ushort8*)(vtp + (size_t)r * SEQ + kt + c);
        }
        if (tid < 64) maskF[tid] = (mask[b * SEQ + kt + tid] > 0) ? 0.f : -1e9f;
        __syncthreads();

        // S = Q·K^T  (C-layout: row=quad*4+r (query), col=l16 (key))
        f32x4 s[2][4];
        float mk[4];
        #pragma unroll
        for (int ni = 0; ni < 4; ++ni) {
            bf16x8 bK0 = *(const bf16x8*)&Ks[(ni * 16 + l16) * PADB + quad * 8];
            bf16x8 bK1 = *(const bf16x8*)&Ks[(ni * 16 + l16) * PADB + 32 + quad * 8];
            mk[ni] = maskF[ni * 16 + l16];
            #pragma unroll
            for (int mi = 0; mi < 2; ++mi) {
                f32x4 t0 = __builtin_amdgcn_mfma_f32_16x16x32_bf16(aQ[mi][0], bK0, zf, 0, 0, 0);
                s[mi][ni] = __builtin_amdgcn_mfma_f32_16x16x32_bf16(aQ[mi][1], bK1, t0, 0, 0, 0);
            }
        }

        // scale + mask; row max over 16 lanes (same quad) + online rescale
        float alpha[2][4];
        #pragma unroll
        for (int mi = 0; mi < 2; ++mi) {
            #pragma unroll
            for (int r = 0; r < 4; ++r) {
                float mx = -3e38f;
                #pragma unroll
                for (int ni = 0; ni < 4; ++ni) {
                    float sv = s[mi][ni][r] * ATTN_SCALE + mk[ni];
                    s[mi][ni][r] = sv;
                    mx = fmaxf(mx, sv);
                }
                mx = fmaxf(mx, __shfl_xor(mx, 1));
                mx = fmaxf(mx, __shfl_xor(mx, 2));
                mx = fmaxf(mx, __shfl_xor(mx, 4));
                mx = fmaxf(mx, __shfl_xor(mx, 8));
                float mo = m_st[mi][r];
                float mn = fmaxf(mo, mx);
                float al = __expf(mo - mn);
                m_st[mi][r] = mn;
                l_st[mi][r] *= al;
                alpha[mi][r] = al;
            }
        }

        // P = exp(S - m) -> LDS (C-layout write), rescale O
        #pragma unroll
        for (int mi = 0; mi < 2; ++mi)
            #pragma unroll
            for (int ni = 0; ni < 4; ++ni)
                #pragma unroll
                for (int r = 0; r < 4; ++r)
                    QP[(w * 32 + mi * 16 + quad * 4 + r) * PADB + ni * 16 + l16]
                        = f2bf(__expf(s[mi][ni][r] - m_st[mi][r]));
        #pragma unroll
        for (int mi = 0; mi < 2; ++mi)
            #pragma unroll
            for (int ni = 0; ni < 4; ++ni)
                #pragma unroll
                for (int r = 0; r < 4; ++r)
                    o[mi][ni][r] *= alpha[mi][r];

        // P back as A-frags (per-wave region; wave-internal LDS ordering)
        bf16x8 aP[2][2];
        #pragma unroll
        for (int mi = 0; mi < 2; ++mi)
            #pragma unroll
            for (int kb = 0; kb < 2; ++kb)
                aP[mi][kb] = *(const bf16x8*)&QP[(w * 32 + mi * 16 + l16) * PADB + kb * 32 + quad * 8];

        // row sums via ones-MFMA (replicated across cols in C-layout)
        f32x4 rs[2];
        #pragma unroll
        for (int mi = 0; mi < 2; ++mi) {
            f32x4 t0 = __builtin_amdgcn_mfma_f32_16x16x32_bf16(aP[mi][0], ones, zf, 0, 0, 0);
            rs[mi] = __builtin_amdgcn_mfma_f32_16x16x32_bf16(aP[mi][1], ones, t0, 0, 0, 0);
        }

        // O += P · V   (B-frag: n=d (row of Vs), k=key (contiguous))
        #pragma unroll
        for (int ni = 0; ni < 4; ++ni) {
            bf16x8 bV0 = *(const bf16x8*)&Vs[(ni * 16 + l16) * PADB + quad * 8];
            bf16x8 bV1 = *(const bf16x8*)&Vs[(ni * 16 + l16) * PADB + 32 + quad * 8];
            #pragma unroll
            for (int mi = 0; mi < 2; ++mi) {
                o[mi][ni] = __builtin_amdgcn_mfma_f32_16x16x32_bf16(aP[mi][0], bV0, o[mi][ni], 0, 0, 0);
                o[mi][ni] = __builtin_amdgcn_mfma_f32_16x16x32_bf16(aP[mi][1], bV1, o[mi][ni], 0, 0, 0);
            }
        }
        #pragma unroll
        for (int mi = 0; mi < 2; ++mi)
            #pragma unroll
            for (int r = 0; r < 4; ++r)
                l_st[mi][r] += rs[mi][r];
    }

    // epilogue: ctx[b, tok, h*64 + d] = O / l
    #pragma unroll
    for (int mi = 0; mi < 2; ++mi)
        #pragma unroll
        for (int r = 0; r < 4; ++r) {
            float inv = 1.f / l_st[mi][r];
            int tok = q0 + w * 32 + mi * 16 + quad * 4 + r;
            #pragma unroll
            for (int ni = 0; ni < 4; ++ni)
                ctxb[(size_t)(b * SEQ + tok) * DMODEL + h * DHEAD + ni * 16 + l16]
                    = f2bf(o[mi][ni][r] * inv);
        }
}

// ---------------------------------------------------------------------------
// LayerNorm, in-place capable (block reads its whole row before writing).
// ---------------------------------------------------------------------------
__global__ __launch_bounds__(256) void ln_kernel(
    const float* __restrict__ y, const float* __restrict__ gamma,
    const float* __restrict__ beta, float* __restrict__ out)
{
    const int t   = blockIdx.x;
    const int tid = threadIdx.x;
    const float* row = y + (size_t)t * DMODEL;

    float vals[3];
    float s = 0.f, s2 = 0.f;
    #pragma unroll
    for (int i = 0; i < 3; ++i) {
        float vv = row[tid + 256 * i];
        vals[i] = vv;
        s  += vv;
        s2 += vv * vv;
    }
    #pragma unroll
    for (int off = 32; off > 0; off >>= 1) {
        s  += __shfl_down(s,  off);
        s2 += __shfl_down(s2, off);
    }
    __shared__ float rbuf[8];
    int w = tid >> 6;
    if ((tid & 63) == 0) { rbuf[w] = s; rbuf[4 + w] = s2; }
    __syncthreads();
    float ts  = rbuf[0] + rbuf[1] + rbuf[2] + rbuf[3];
    float ts2 = rbuf[4] + rbuf[5] + rbuf[6] + rbuf[7];
    float mu  = ts * (1.f / DMODEL);
    float var = ts2 * (1.f / DMODEL) - mu * mu;
    float inv = rsqrtf(var + LN_EPS);
    #pragma unroll
    for (int i = 0; i < 3; ++i) {
        int c = tid + 256 * i;
        out[(size_t)t * DMODEL + c] = gamma[c] * (vals[i] - mu) * inv + beta[c];
    }
}

// ---------------------------------------------------------------------------
extern "C" void kernel_launch(void* const* d_in, const int* in_sizes, int n_in,
                              void* d_out, int out_size, void* d_ws, size_t ws_size,
                              hipStream_t stream) {
    const float* x     = (const float*)d_in[0];
    const int*   mask  = (const int*)  d_in[1];
    const float* Wq    = (const float*)d_in[2];
    const float* bq    = (const float*)d_in[3];
    const float* Wk    = (const float*)d_in[4];
    const float* bk    = (const float*)d_in[5];
    const float* Wv    = (const float*)d_in[6];
    const float* bv    = (const float*)d_in[7];
    const float* Wo    = (const float*)d_in[8];
    const float* bo    = (const float*)d_in[9];
    const float* gamma = (const float*)d_in[10];
    const float* beta  = (const float*)d_in[11];
    float* out = (float*)d_out;

    const size_t perTok = (size_t)NTOK * DMODEL;   // 6,291,456
    const size_t perW   = (size_t)DMODEL * DMODEL; //   589,824

    unsigned short* xb   = (unsigned short*)d_ws;
    unsigned short* wtq  = xb + perTok;
    unsigned short* wtk  = wtq + perW;
    unsigned short* wtv  = wtk + perW;
    unsigned short* wto  = wtv + perW;
    unsigned short* qb   = wto + perW;
    unsigned short* kb   = qb + perTok;
    unsigned short* vb   = kb + perTok;    // holds V^T: [B,H,DH,SEQ]
    unsigned short* ctxb = vb + perTok;
    float* y = out;   // O-proj output lives in d_out; LN runs in-place

    cast_x_kernel<<<perTok / 1024, 256, 0, stream>>>(x, xb);
    prep_wt_kernel<<<dim3(24, 24, 4), 256, 0, stream>>>(Wq, Wk, Wv, Wo, wtq, wtk, wtv, wto);

    mfma_gemm_qkv<<<dim3(NTOK / 128, DMODEL / 128, 3), 256, 0, stream>>>(
        xb, wtq, wtk, wtv, bq, bk, bv, qb, kb, vb);

    attn_mfma_kernel<<<dim3(SEQ / 128, NH, BATCH), 256, 0, stream>>>(qb, kb, vb, mask, ctxb);

    mfma_gemm_oproj<<<dim3(NTOK / 128, DMODEL / 128), 256, 0, stream>>>(
        ctxb, wto, bo, x, y);

    ln_kernel<<<NTOK, 256, 0, stream>>>(y, gamma, beta, out);
}

// Round 5
// 217.228 us; speedup vs baseline: 1.1345x; 1.1345x over previous
//
#include <hip/hip_runtime.h>
#include <math.h>

#define NH 12
#define DMODEL 768
#define DHEAD 64
#define BATCH 16
#define SEQ 512
#define NTOK (BATCH*SEQ)   // 8192
#define ATTN_SCALE 0.125f
#define LN_EPS 1e-3f
#define PADB 72            // padded LDS row length (bf16) for attention tiles
#define KITERS (DMODEL/64) // 12 (BK=64)

typedef __attribute__((ext_vector_type(8))) short  bf16x8;
typedef __attribute__((ext_vector_type(8))) unsigned short ushort8;
typedef __attribute__((ext_vector_type(4))) float  f32x4;

__device__ __forceinline__ unsigned short f2bf(float f) {
    unsigned int u = __float_as_uint(f);
    unsigned int r = (u + 0x7fffu + ((u >> 16) & 1u)) >> 16;
    return (unsigned short)r;
}
__device__ __forceinline__ float bf2f(unsigned short h) {
    return __uint_as_float(((unsigned int)h) << 16);
}

__device__ __forceinline__ void async_copy16(const void* g, void* l) {
    __builtin_amdgcn_global_load_lds((const __attribute__((address_space(1))) void*)g,
                                     (__attribute__((address_space(3))) void*)l,
                                     16, 0, 0);
}

// ---------------------------------------------------------------------------
// Merged prep: blocks [0,6144) cast x fp32->bf16; blocks [6144,8448) build
// Wt[n][k] = bf16(W[k][n]) for the 4 weight matrices.
// ---------------------------------------------------------------------------
__global__ __launch_bounds__(256) void prep_kernel(
    const float* __restrict__ x,
    const float* __restrict__ Wq, const float* __restrict__ Wk,
    const float* __restrict__ Wv, const float* __restrict__ Wo,
    unsigned short* __restrict__ xb,
    unsigned short* __restrict__ tq, unsigned short* __restrict__ tk,
    unsigned short* __restrict__ tv, unsigned short* __restrict__ to_)
{
    __shared__ float tile[32][33];
    const int bid = blockIdx.x;
    const int tid = threadIdx.x;

    if (bid < 6144) {
        int i = (bid * 256 + tid) * 4;
        const float4 v = *(const float4*)(x + i);
        unsigned long long pack =
              (unsigned long long)f2bf(v.x)
            | ((unsigned long long)f2bf(v.y) << 16)
            | ((unsigned long long)f2bf(v.z) << 32)
            | ((unsigned long long)f2bf(v.w) << 48);
        *(unsigned long long*)(xb + i) = pack;
        return;
    }

    const int t   = bid - 6144;       // 0..2303
    const int zz  = t / 576;
    const int rem = t % 576;
    const float* W = (zz == 0) ? Wq : (zz == 1) ? Wk : (zz == 2) ? Wv : Wo;
    unsigned short* T = (zz == 0) ? tq : (zz == 1) ? tk : (zz == 2) ? tv : to_;

    const int bx = (rem / 24) * 32;   // k base
    const int by = (rem % 24) * 32;   // n base
    const int tx = tid & 31, ty = tid >> 5;   // ty 0..7

    #pragma unroll
    for (int i = 0; i < 32; i += 8)
        tile[ty + i][tx] = W[(size_t)(bx + ty + i) * DMODEL + by + tx];
    __syncthreads();
    #pragma unroll
    for (int i = 0; i < 32; i += 8)
        T[(size_t)(by + ty + i) * DMODEL + bx + tx] = f2bf(tile[tx][ty + i]);
}

// ---------------------------------------------------------------------------
// MFMA GEMM, single-buffered (dbuf measured -13% in R4), BK=64, 128x128 tile,
// XOR-swizzled LDS: 16B chunk c of row r stored at chunk-pos c^(r&7) ->
// frag ds_read_b128 hits 2-way banks (free) instead of 8-way (+4cyc each,
// SQ_LDS_BANK_CONFLICT=3.5M in R3/R4). global_load_lds lane->global mapping
// permuted to match (still 128B-coalesced per 8 lanes).
// QKV variant: bias; Q,K scatter [B,H,L,DH]; V scatter transposed [B,H,DH,SEQ].
// ---------------------------------------------------------------------------
__global__ __launch_bounds__(256, 4) void mfma_gemm_qkv(
    const unsigned short* __restrict__ xb,
    const unsigned short* __restrict__ wt0, const unsigned short* __restrict__ wt1,
    const unsigned short* __restrict__ wt2,
    const float* __restrict__ b0, const float* __restrict__ b1, const float* __restrict__ b2,
    unsigned short* __restrict__ o0, unsigned short* __restrict__ o1,
    unsigned short* __restrict__ o2)
{
    __shared__ __align__(16) unsigned short As[128 * 64];
    __shared__ __align__(16) unsigned short Bs[128 * 64];

    const int zz = blockIdx.z;
    const unsigned short* Wt = (zz == 0) ? wt0 : (zz == 1) ? wt1 : wt2;
    const float* bias        = (zz == 0) ? b0  : (zz == 1) ? b1  : b2;
    unsigned short* out      = (zz == 0) ? o0  : (zz == 1) ? o1  : o2;

    const int tid  = threadIdx.x;
    const int lane = tid & 63;
    const int w    = tid >> 6;
    const int wm   = w >> 1, wn = w & 1;
    const int m0   = blockIdx.x * 128;
    const int n0   = blockIdx.y * 128;
    const int quad = lane >> 4;
    const int l16  = lane & 15;

    // staging geometry: 16 insts of 1KB each for A (8 rows x 8 chunks), 4/wave
    const int rloc = lane >> 3;               // 0..7 row-within-inst
    const int csw  = (lane & 7) ^ rloc;       // swizzled logical chunk
    int rowS[4];
    #pragma unroll
    for (int ii = 0; ii < 4; ++ii) rowS[ii] = (4 * w + ii) * 8 + rloc;

    // frag-read swizzle: chunk-pos offset (in shorts) for ksub0; ksub1 = ^32
    const int p0 = ((quad ^ (l16 & 7)) * 8);

    f32x4 acc[4][4] = {};

    for (int kb = 0; kb < KITERS; ++kb) {
        const int k0 = kb * 64;
        #pragma unroll
        for (int ii = 0; ii < 4; ++ii) {
            async_copy16(xb + (size_t)(m0 + rowS[ii]) * DMODEL + k0 + csw * 8,
                         As + (4 * w + ii) * 512);
            async_copy16(Wt + (size_t)(n0 + rowS[ii]) * DMODEL + k0 + csw * 8,
                         Bs + (4 * w + ii) * 512);
        }
        __syncthreads();

        #pragma unroll
        for (int ks = 0; ks < 2; ++ks) {
            const int po = p0 ^ (ks * 32);
            bf16x8 a[4], b[4];
            #pragma unroll
            for (int mi = 0; mi < 4; ++mi)
                a[mi] = *(const bf16x8*)&As[(wm * 64 + mi * 16 + l16) * 64 + po];
            #pragma unroll
            for (int ni = 0; ni < 4; ++ni)
                b[ni] = *(const bf16x8*)&Bs[(wn * 64 + ni * 16 + l16) * 64 + po];
            #pragma unroll
            for (int mi = 0; mi < 4; ++mi)
                #pragma unroll
                for (int ni = 0; ni < 4; ++ni)
                    acc[mi][ni] = __builtin_amdgcn_mfma_f32_16x16x32_bf16(a[mi], b[ni], acc[mi][ni], 0, 0, 0);
        }
        __syncthreads();
    }

    if (zz == 2) {
        #pragma unroll
        for (int ni = 0; ni < 4; ++ni) {
            const int ncol = n0 + wn * 64 + ni * 16 + l16;
            const int h = ncol >> 6, dh = ncol & 63;
            const float bv = bias[ncol];
            #pragma unroll
            for (int mi = 0; mi < 4; ++mi) {
                const int mbase = m0 + wm * 64 + mi * 16 + quad * 4;
                const int bi = mbase >> 9, l = mbase & 511;
                unsigned long long pack = 0;
                #pragma unroll
                for (int r = 0; r < 4; ++r)
                    pack |= (unsigned long long)f2bf(acc[mi][ni][r] + bv) << (16 * r);
                *(unsigned long long*)(out + ((size_t)((bi * NH + h) * DHEAD + dh)) * SEQ + l) = pack;
            }
        }
    } else {
        #pragma unroll
        for (int ni = 0; ni < 4; ++ni) {
            const int ncol = n0 + wn * 64 + ni * 16 + l16;
            const int h = ncol >> 6, dh = ncol & 63;
            const float bv = bias[ncol];
            #pragma unroll
            for (int mi = 0; mi < 4; ++mi) {
                const int mbase = m0 + wm * 64 + mi * 16 + quad * 4;
                #pragma unroll
                for (int r = 0; r < 4; ++r) {
                    const int t = mbase + r;
                    const int bi = t >> 9, l = t & 511;
                    out[(size_t)((bi * NH + h) * SEQ + l) * DHEAD + dh] = f2bf(acc[mi][ni][r] + bv);
                }
            }
        }
    }
}

// O-proj variant: y = ctx @ Wo + bo + x (fp32 out), same swizzled BK=64 loop.
__global__ __launch_bounds__(256, 4) void mfma_gemm_oproj(
    const unsigned short* __restrict__ ctxb, const unsigned short* __restrict__ wto,
    const float* __restrict__ bo, const float* __restrict__ x,
    float* __restrict__ y)
{
    __shared__ __align__(16) unsigned short As[128 * 64];
    __shared__ __align__(16) unsigned short Bs[128 * 64];

    const int tid  = threadIdx.x;
    const int lane = tid & 63;
    const int w    = tid >> 6;
    const int wm   = w >> 1, wn = w & 1;
    const int m0   = blockIdx.x * 128;
    const int n0   = blockIdx.y * 128;
    const int quad = lane >> 4;
    const int l16  = lane & 15;

    const int rloc = lane >> 3;
    const int csw  = (lane & 7) ^ rloc;
    int rowS[4];
    #pragma unroll
    for (int ii = 0; ii < 4; ++ii) rowS[ii] = (4 * w + ii) * 8 + rloc;
    const int p0 = ((quad ^ (l16 & 7)) * 8);

    f32x4 acc[4][4] = {};

    for (int kb = 0; kb < KITERS; ++kb) {
        const int k0 = kb * 64;
        #pragma unroll
        for (int ii = 0; ii < 4; ++ii) {
            async_copy16(ctxb + (size_t)(m0 + rowS[ii]) * DMODEL + k0 + csw * 8,
                         As + (4 * w + ii) * 512);
            async_copy16(wto  + (size_t)(n0 + rowS[ii]) * DMODEL + k0 + csw * 8,
                         Bs + (4 * w + ii) * 512);
        }
        __syncthreads();

        #pragma unroll
        for (int ks = 0; ks < 2; ++ks) {
            const int po = p0 ^ (ks * 32);
            bf16x8 a[4], b[4];
            #pragma unroll
            for (int mi = 0; mi < 4; ++mi)
                a[mi] = *(const bf16x8*)&As[(wm * 64 + mi * 16 + l16) * 64 + po];
            #pragma unroll
            for (int ni = 0; ni < 4; ++ni)
                b[ni] = *(const bf16x8*)&Bs[(wn * 64 + ni * 16 + l16) * 64 + po];
            #pragma unroll
            for (int mi = 0; mi < 4; ++mi)
                #pragma unroll
                for (int ni = 0; ni < 4; ++ni)
                    acc[mi][ni] = __builtin_amdgcn_mfma_f32_16x16x32_bf16(a[mi], b[ni], acc[mi][ni], 0, 0, 0);
        }
        __syncthreads();
    }

    #pragma unroll
    for (int ni = 0; ni < 4; ++ni) {
        const int ncol = n0 + wn * 64 + ni * 16 + l16;
        const float bv = bo[ncol];
        #pragma unroll
        for (int mi = 0; mi < 4; ++mi) {
            const int mbase = m0 + wm * 64 + mi * 16 + quad * 4;
            #pragma unroll
            for (int r = 0; r < 4; ++r) {
                const size_t idx = (size_t)(mbase + r) * DMODEL + ncol;
                y[idx] = acc[mi][ni][r] + bv + x[idx];
            }
        }
    }
}

// ---------------------------------------------------------------------------
// MFMA flash attention (unchanged from R3). Block = (b,h,128-q tile).
// ---------------------------------------------------------------------------
__global__ __launch_bounds__(256) void attn_mfma_kernel(
    const unsigned short* __restrict__ q, const unsigned short* __restrict__ k,
    const unsigned short* __restrict__ vt, const int* __restrict__ mask,
    unsigned short* __restrict__ ctxb)
{
    __shared__ __align__(16) unsigned short Ks[64 * PADB];
    __shared__ __align__(16) unsigned short Vs[64 * PADB];   // V^T tile: [d][key]
    __shared__ __align__(16) unsigned short QP[128 * PADB];  // Q staging, then P
    __shared__ float maskF[64];

    const int tid  = threadIdx.x;
    const int lane = tid & 63;
    const int w    = tid >> 6;
    const int quad = lane >> 4;
    const int l16  = lane & 15;
    const int q0   = blockIdx.x * 128;
    const int h    = blockIdx.y;
    const int b    = blockIdx.z;

    const unsigned short* qp  = q  + ((size_t)(b * NH + h) * SEQ + q0) * DHEAD;
    const unsigned short* kp  = k  + (size_t)(b * NH + h) * SEQ * DHEAD;
    const unsigned short* vtp = vt + (size_t)(b * NH + h) * DHEAD * SEQ;

    #pragma unroll
    for (int i = 0; i < 4; ++i) {
        int idx = tid * 8 + 2048 * i;
        *(ushort8*)&QP[(idx >> 6) * PADB + (idx & 63)] = *(const ushort8*)(qp + idx);
    }
    __syncthreads();

    bf16x8 aQ[2][2];
    #pragma unroll
    for (int mi = 0; mi < 2; ++mi)
        #pragma unroll
        for (int kb = 0; kb < 2; ++kb)
            aQ[mi][kb] = *(const bf16x8*)&QP[(w * 32 + mi * 16 + l16) * PADB + kb * 32 + quad * 8];

    bf16x8 ones;
    #pragma unroll
    for (int j = 0; j < 8; ++j) ones[j] = (short)0x3F80;   // bf16 1.0

    float m_st[2][4], l_st[2][4];
    #pragma unroll
    for (int mi = 0; mi < 2; ++mi)
        #pragma unroll
        for (int r = 0; r < 4; ++r) { m_st[mi][r] = -1e30f; l_st[mi][r] = 0.f; }
    f32x4 o[2][4] = {};
    const f32x4 zf = {0.f, 0.f, 0.f, 0.f};

    for (int kt = 0; kt < SEQ; kt += 64) {
        __syncthreads();
        #pragma unroll
        for (int i = 0; i < 2; ++i) {
            int idx = tid * 8 + 2048 * i;
            int r = idx >> 6, c = idx & 63;
            *(ushort8*)&Ks[r * PADB + c] = *(const ushort8*)(kp + (size_t)kt * DHEAD + idx);
            *(ushort8*)&Vs[r * PADB + c] = *(const ushort8*)(vtp + (size_t)r * SEQ + kt + c);
        }
        if (tid < 64) maskF[tid] = (mask[b * SEQ + kt + tid] > 0) ? 0.f : -1e9f;
        __syncthreads();

        f32x4 s[2][4];
        float mk[4];
        #pragma unroll
        for (int ni = 0; ni < 4; ++ni) {
            bf16x8 bK0 = *(const bf16x8*)&Ks[(ni * 16 + l16) * PADB + quad * 8];
            bf16x8 bK1 = *(const bf16x8*)&Ks[(ni * 16 + l16) * PADB + 32 + quad * 8];
            mk[ni] = maskF[ni * 16 + l16];
            #pragma unroll
            for (int mi = 0; mi < 2; ++mi) {
                f32x4 t0 = __builtin_amdgcn_mfma_f32_16x16x32_bf16(aQ[mi][0], bK0, zf, 0, 0, 0);
                s[mi][ni] = __builtin_amdgcn_mfma_f32_16x16x32_bf16(aQ[mi][1], bK1, t0, 0, 0, 0);
            }
        }

        float alpha[2][4];
        #pragma unroll
        for (int mi = 0; mi < 2; ++mi) {
            #pragma unroll
            for (int r = 0; r < 4; ++r) {
                float mx = -3e38f;
                #pragma unroll
                for (int ni = 0; ni < 4; ++ni) {
                    float sv = s[mi][ni][r] * ATTN_SCALE + mk[ni];
                    s[mi][ni][r] = sv;
                    mx = fmaxf(mx, sv);
                }
                mx = fmaxf(mx, __shfl_xor(mx, 1));
                mx = fmaxf(mx, __shfl_xor(mx, 2));
                mx = fmaxf(mx, __shfl_xor(mx, 4));
                mx = fmaxf(mx, __shfl_xor(mx, 8));
                float mo = m_st[mi][r];
                float mn = fmaxf(mo, mx);
                float al = __expf(mo - mn);
                m_st[mi][r] = mn;
                l_st[mi][r] *= al;
                alpha[mi][r] = al;
            }
        }

        #pragma unroll
        for (int mi = 0; mi < 2; ++mi)
            #pragma unroll
            for (int ni = 0; ni < 4; ++ni)
                #pragma unroll
                for (int r = 0; r < 4; ++r)
                    QP[(w * 32 + mi * 16 + quad * 4 + r) * PADB + ni * 16 + l16]
                        = f2bf(__expf(s[mi][ni][r] - m_st[mi][r]));
        #pragma unroll
        for (int mi = 0; mi < 2; ++mi)
            #pragma unroll
            for (int ni = 0; ni < 4; ++ni)
                #pragma unroll
                for (int r = 0; r < 4; ++r)
                    o[mi][ni][r] *= alpha[mi][r];

        bf16x8 aP[2][2];
        #pragma unroll
        for (int mi = 0; mi < 2; ++mi)
            #pragma unroll
            for (int kb = 0; kb < 2; ++kb)
                aP[mi][kb] = *(const bf16x8*)&QP[(w * 32 + mi * 16 + l16) * PADB + kb * 32 + quad * 8];

        f32x4 rs[2];
        #pragma unroll
        for (int mi = 0; mi < 2; ++mi) {
            f32x4 t0 = __builtin_amdgcn_mfma_f32_16x16x32_bf16(aP[mi][0], ones, zf, 0, 0, 0);
            rs[mi] = __builtin_amdgcn_mfma_f32_16x16x32_bf16(aP[mi][1], ones, t0, 0, 0, 0);
        }

        #pragma unroll
        for (int ni = 0; ni < 4; ++ni) {
            bf16x8 bV0 = *(const bf16x8*)&Vs[(ni * 16 + l16) * PADB + quad * 8];
            bf16x8 bV1 = *(const bf16x8*)&Vs[(ni * 16 + l16) * PADB + 32 + quad * 8];
            #pragma unroll
            for (int mi = 0; mi < 2; ++mi) {
                o[mi][ni] = __builtin_amdgcn_mfma_f32_16x16x32_bf16(aP[mi][0], bV0, o[mi][ni], 0, 0, 0);
                o[mi][ni] = __builtin_amdgcn_mfma_f32_16x16x32_bf16(aP[mi][1], bV1, o[mi][ni], 0, 0, 0);
            }
        }
        #pragma unroll
        for (int mi = 0; mi < 2; ++mi)
            #pragma unroll
            for (int r = 0; r < 4; ++r)
                l_st[mi][r] += rs[mi][r];
    }

    #pragma unroll
    for (int mi = 0; mi < 2; ++mi)
        #pragma unroll
        for (int r = 0; r < 4; ++r) {
            float inv = 1.f / l_st[mi][r];
            int tok = q0 + w * 32 + mi * 16 + quad * 4 + r;
            #pragma unroll
            for (int ni = 0; ni < 4; ++ni)
                ctxb[(size_t)(b * SEQ + tok) * DMODEL + h * DHEAD + ni * 16 + l16]
                    = f2bf(o[mi][ni][r] * inv);
        }
}

// ---------------------------------------------------------------------------
// LayerNorm, in-place capable.
// ---------------------------------------------------------------------------
__global__ __launch_bounds__(256) void ln_kernel(
    const float* __restrict__ y, const float* __restrict__ gamma,
    const float* __restrict__ beta, float* __restrict__ out)
{
    const int t   = blockIdx.x;
    const int tid = threadIdx.x;
    const float* row = y + (size_t)t * DMODEL;

    float vals[3];
    float s = 0.f, s2 = 0.f;
    #pragma unroll
    for (int i = 0; i < 3; ++i) {
        float vv = row[tid + 256 * i];
        vals[i] = vv;
        s  += vv;
        s2 += vv * vv;
    }
    #pragma unroll
    for (int off = 32; off > 0; off >>= 1) {
        s  += __shfl_down(s,  off);
        s2 += __shfl_down(s2, off);
    }
    __shared__ float rbuf[8];
    int w = tid >> 6;
    if ((tid & 63) == 0) { rbuf[w] = s; rbuf[4 + w] = s2; }
    __syncthreads();
    float ts  = rbuf[0] + rbuf[1] + rbuf[2] + rbuf[3];
    float ts2 = rbuf[4] + rbuf[5] + rbuf[6] + rbuf[7];
    float mu  = ts * (1.f / DMODEL);
    float var = ts2 * (1.f / DMODEL) - mu * mu;
    float inv = rsqrtf(var + LN_EPS);
    #pragma unroll
    for (int i = 0; i < 3; ++i) {
        int c = tid + 256 * i;
        out[(size_t)t * DMODEL + c] = gamma[c] * (vals[i] - mu) * inv + beta[c];
    }
}

// ---------------------------------------------------------------------------
extern "C" void kernel_launch(void* const* d_in, const int* in_sizes, int n_in,
                              void* d_out, int out_size, void* d_ws, size_t ws_size,
                              hipStream_t stream) {
    const float* x     = (const float*)d_in[0];
    const int*   mask  = (const int*)  d_in[1];
    const float* Wq    = (const float*)d_in[2];
    const float* bq    = (const float*)d_in[3];
    const float* Wk    = (const float*)d_in[4];
    const float* bk    = (const float*)d_in[5];
    const float* Wv    = (const float*)d_in[6];
    const float* bv    = (const float*)d_in[7];
    const float* Wo    = (const float*)d_in[8];
    const float* bo    = (const float*)d_in[9];
    const float* gamma = (const float*)d_in[10];
    const float* beta  = (const float*)d_in[11];
    float* out = (float*)d_out;

    const size_t perTok = (size_t)NTOK * DMODEL;   // 6,291,456
    const size_t perW   = (size_t)DMODEL * DMODEL; //   589,824

    unsigned short* xb   = (unsigned short*)d_ws;
    unsigned short* wtq  = xb + perTok;
    unsigned short* wtk  = wtq + perW;
    unsigned short* wtv  = wtk + perW;
    unsigned short* wto  = wtv + perW;
    unsigned short* qb   = wto + perW;
    unsigned short* kb   = qb + perTok;
    unsigned short* vb   = kb + perTok;    // holds V^T: [B,H,DH,SEQ]
    unsigned short* ctxb = vb + perTok;
    float* y = out;   // O-proj output lives in d_out; LN runs in-place

    prep_kernel<<<6144 + 2304, 256, 0, stream>>>(
        x, Wq, Wk, Wv, Wo, xb, wtq, wtk, wtv, wto);

    mfma_gemm_qkv<<<dim3(NTOK / 128, DMODEL / 128, 3), 256, 0, stream>>>(
        xb, wtq, wtk, wtv, bq, bk, bv, qb, kb, vb);

    attn_mfma_kernel<<<dim3(SEQ / 128, NH, BATCH), 256, 0, stream>>>(qb, kb, vb, mask, ctxb);

    mfma_gemm_oproj<<<dim3(NTOK / 128, DMODEL / 128), 256, 0, stream>>>(
        ctxb, wto, bo, x, y);

    ln_kernel<<<NTOK, 256, 0, stream>>>(y, gamma, beta, out);
}

// Round 6
// 214.241 us; speedup vs baseline: 1.1503x; 1.0139x over previous
//
#include <hip/hip_runtime.h>
#include <math.h>

#define NH 12
#define DMODEL 768
#define DHEAD 64
#define BATCH 16
#define SEQ 512
#define NTOK (BATCH*SEQ)   // 8192
#define ATTN_SCALE 0.125f
#define LN_EPS 1e-3f
#define PADP 72            // padded LDS row length (shorts) for the P tile
#define KITERS (DMODEL/64) // 12 (BK=64)

typedef __attribute__((ext_vector_type(8))) short  bf16x8;
typedef __attribute__((ext_vector_type(8))) unsigned short ushort8;
typedef __attribute__((ext_vector_type(4))) float  f32x4;

__device__ __forceinline__ unsigned short f2bf(float f) {
    unsigned int u = __float_as_uint(f);
    unsigned int r = (u + 0x7fffu + ((u >> 16) & 1u)) >> 16;
    return (unsigned short)r;
}

__device__ __forceinline__ void async_copy16(const void* g, void* l) {
    __builtin_amdgcn_global_load_lds((const __attribute__((address_space(1))) void*)g,
                                     (__attribute__((address_space(3))) void*)l,
                                     16, 0, 0);
}

// ---------------------------------------------------------------------------
// Merged prep: blocks [0,6144) cast x fp32->bf16; blocks [6144,8448) build
// Wt[n][k] = bf16(W[k][n]) for the 4 weight matrices.
// ---------------------------------------------------------------------------
__global__ __launch_bounds__(256) void prep_kernel(
    const float* __restrict__ x,
    const float* __restrict__ Wq, const float* __restrict__ Wk,
    const float* __restrict__ Wv, const float* __restrict__ Wo,
    unsigned short* __restrict__ xb,
    unsigned short* __restrict__ tq, unsigned short* __restrict__ tk,
    unsigned short* __restrict__ tv, unsigned short* __restrict__ to_)
{
    __shared__ float tile[32][33];
    const int bid = blockIdx.x;
    const int tid = threadIdx.x;

    if (bid < 6144) {
        int i = (bid * 256 + tid) * 4;
        const float4 v = *(const float4*)(x + i);
        unsigned long long pack =
              (unsigned long long)f2bf(v.x)
            | ((unsigned long long)f2bf(v.y) << 16)
            | ((unsigned long long)f2bf(v.z) << 32)
            | ((unsigned long long)f2bf(v.w) << 48);
        *(unsigned long long*)(xb + i) = pack;
        return;
    }

    const int t   = bid - 6144;       // 0..2303
    const int zz  = t / 576;
    const int rem = t % 576;
    const float* W = (zz == 0) ? Wq : (zz == 1) ? Wk : (zz == 2) ? Wv : Wo;
    unsigned short* T = (zz == 0) ? tq : (zz == 1) ? tk : (zz == 2) ? tv : to_;

    const int bx = (rem / 24) * 32;   // k base
    const int by = (rem % 24) * 32;   // n base
    const int tx = tid & 31, ty = tid >> 5;   // ty 0..7

    #pragma unroll
    for (int i = 0; i < 32; i += 8)
        tile[ty + i][tx] = W[(size_t)(bx + ty + i) * DMODEL + by + tx];
    __syncthreads();
    #pragma unroll
    for (int i = 0; i < 32; i += 8)
        T[(size_t)(by + ty + i) * DMODEL + bx + tx] = f2bf(tile[tx][ty + i]);
}

// ---------------------------------------------------------------------------
// MFMA GEMM, single-buffered, BK=64, 128x128 tile, XOR-swizzled LDS (R5).
// QKV variant: bias; Q scaled by ATTN_SCALE (folded, free); Q,K scatter
// [B,H,L,DH]; V scatter transposed [B,H,DH,SEQ].
// ---------------------------------------------------------------------------
__global__ __launch_bounds__(256, 4) void mfma_gemm_qkv(
    const unsigned short* __restrict__ xb,
    const unsigned short* __restrict__ wt0, const unsigned short* __restrict__ wt1,
    const unsigned short* __restrict__ wt2,
    const float* __restrict__ b0, const float* __restrict__ b1, const float* __restrict__ b2,
    unsigned short* __restrict__ o0, unsigned short* __restrict__ o1,
    unsigned short* __restrict__ o2)
{
    __shared__ __align__(16) unsigned short As[128 * 64];
    __shared__ __align__(16) unsigned short Bs[128 * 64];

    const int zz = blockIdx.z;
    const unsigned short* Wt = (zz == 0) ? wt0 : (zz == 1) ? wt1 : wt2;
    const float* bias        = (zz == 0) ? b0  : (zz == 1) ? b1  : b2;
    unsigned short* out      = (zz == 0) ? o0  : (zz == 1) ? o1  : o2;
    const float sc           = (zz == 0) ? ATTN_SCALE : 1.0f;

    const int tid  = threadIdx.x;
    const int lane = tid & 63;
    const int w    = tid >> 6;
    const int wm   = w >> 1, wn = w & 1;
    const int m0   = blockIdx.x * 128;
    const int n0   = blockIdx.y * 128;
    const int quad = lane >> 4;
    const int l16  = lane & 15;

    const int rloc = lane >> 3;               // 0..7 row-within-inst
    const int csw  = (lane & 7) ^ rloc;       // swizzled logical chunk
    int rowS[4];
    #pragma unroll
    for (int ii = 0; ii < 4; ++ii) rowS[ii] = (4 * w + ii) * 8 + rloc;

    const int p0 = ((quad ^ (l16 & 7)) * 8);

    f32x4 acc[4][4] = {};

    for (int kb = 0; kb < KITERS; ++kb) {
        const int k0 = kb * 64;
        #pragma unroll
        for (int ii = 0; ii < 4; ++ii) {
            async_copy16(xb + (size_t)(m0 + rowS[ii]) * DMODEL + k0 + csw * 8,
                         As + (4 * w + ii) * 512);
            async_copy16(Wt + (size_t)(n0 + rowS[ii]) * DMODEL + k0 + csw * 8,
                         Bs + (4 * w + ii) * 512);
        }
        __syncthreads();

        #pragma unroll
        for (int ks = 0; ks < 2; ++ks) {
            const int po = p0 ^ (ks * 32);
            bf16x8 a[4], b[4];
            #pragma unroll
            for (int mi = 0; mi < 4; ++mi)
                a[mi] = *(const bf16x8*)&As[(wm * 64 + mi * 16 + l16) * 64 + po];
            #pragma unroll
            for (int ni = 0; ni < 4; ++ni)
                b[ni] = *(const bf16x8*)&Bs[(wn * 64 + ni * 16 + l16) * 64 + po];
            #pragma unroll
            for (int mi = 0; mi < 4; ++mi)
                #pragma unroll
                for (int ni = 0; ni < 4; ++ni)
                    acc[mi][ni] = __builtin_amdgcn_mfma_f32_16x16x32_bf16(a[mi], b[ni], acc[mi][ni], 0, 0, 0);
        }
        __syncthreads();
    }

    if (zz == 2) {
        #pragma unroll
        for (int ni = 0; ni < 4; ++ni) {
            const int ncol = n0 + wn * 64 + ni * 16 + l16;
            const int h = ncol >> 6, dh = ncol & 63;
            const float bv = bias[ncol];
            #pragma unroll
            for (int mi = 0; mi < 4; ++mi) {
                const int mbase = m0 + wm * 64 + mi * 16 + quad * 4;
                const int bi = mbase >> 9, l = mbase & 511;
                unsigned long long pack = 0;
                #pragma unroll
                for (int r = 0; r < 4; ++r)
                    pack |= (unsigned long long)f2bf(acc[mi][ni][r] + bv) << (16 * r);
                *(unsigned long long*)(out + ((size_t)((bi * NH + h) * DHEAD + dh)) * SEQ + l) = pack;
            }
        }
    } else {
        #pragma unroll
        for (int ni = 0; ni < 4; ++ni) {
            const int ncol = n0 + wn * 64 + ni * 16 + l16;
            const int h = ncol >> 6, dh = ncol & 63;
            const float bv = bias[ncol];
            #pragma unroll
            for (int mi = 0; mi < 4; ++mi) {
                const int mbase = m0 + wm * 64 + mi * 16 + quad * 4;
                #pragma unroll
                for (int r = 0; r < 4; ++r) {
                    const int t = mbase + r;
                    const int bi = t >> 9, l = t & 511;
                    out[(size_t)((bi * NH + h) * SEQ + l) * DHEAD + dh] = f2bf((acc[mi][ni][r] + bv) * sc);
                }
            }
        }
    }
}

// O-proj variant: y = ctx @ Wo + bo + x (fp32 out), same swizzled BK=64 loop.
__global__ __launch_bounds__(256, 4) void mfma_gemm_oproj(
    const unsigned short* __restrict__ ctxb, const unsigned short* __restrict__ wto,
    const float* __restrict__ bo, const float* __restrict__ x,
    float* __restrict__ y)
{
    __shared__ __align__(16) unsigned short As[128 * 64];
    __shared__ __align__(16) unsigned short Bs[128 * 64];

    const int tid  = threadIdx.x;
    const int lane = tid & 63;
    const int w    = tid >> 6;
    const int wm   = w >> 1, wn = w & 1;
    const int m0   = blockIdx.x * 128;
    const int n0   = blockIdx.y * 128;
    const int quad = lane >> 4;
    const int l16  = lane & 15;

    const int rloc = lane >> 3;
    const int csw  = (lane & 7) ^ rloc;
    int rowS[4];
    #pragma unroll
    for (int ii = 0; ii < 4; ++ii) rowS[ii] = (4 * w + ii) * 8 + rloc;
    const int p0 = ((quad ^ (l16 & 7)) * 8);

    f32x4 acc[4][4] = {};

    for (int kb = 0; kb < KITERS; ++kb) {
        const int k0 = kb * 64;
        #pragma unroll
        for (int ii = 0; ii < 4; ++ii) {
            async_copy16(ctxb + (size_t)(m0 + rowS[ii]) * DMODEL + k0 + csw * 8,
                         As + (4 * w + ii) * 512);
            async_copy16(wto  + (size_t)(n0 + rowS[ii]) * DMODEL + k0 + csw * 8,
                         Bs + (4 * w + ii) * 512);
        }
        __syncthreads();

        #pragma unroll
        for (int ks = 0; ks < 2; ++ks) {
            const int po = p0 ^ (ks * 32);
            bf16x8 a[4], b[4];
            #pragma unroll
            for (int mi = 0; mi < 4; ++mi)
                a[mi] = *(const bf16x8*)&As[(wm * 64 + mi * 16 + l16) * 64 + po];
            #pragma unroll
            for (int ni = 0; ni < 4; ++ni)
                b[ni] = *(const bf16x8*)&Bs[(wn * 64 + ni * 16 + l16) * 64 + po];
            #pragma unroll
            for (int mi = 0; mi < 4; ++mi)
                #pragma unroll
                for (int ni = 0; ni < 4; ++ni)
                    acc[mi][ni] = __builtin_amdgcn_mfma_f32_16x16x32_bf16(a[mi], b[ni], acc[mi][ni], 0, 0, 0);
        }
        __syncthreads();
    }

    #pragma unroll
    for (int ni = 0; ni < 4; ++ni) {
        const int ncol = n0 + wn * 64 + ni * 16 + l16;
        const float bv = bo[ncol];
        #pragma unroll
        for (int mi = 0; mi < 4; ++mi) {
            const int mbase = m0 + wm * 64 + mi * 16 + quad * 4;
            #pragma unroll
            for (int r = 0; r < 4; ++r) {
                const size_t idx = (size_t)(mbase + r) * DMODEL + ncol;
                y[idx] = acc[mi][ni][r] + bv + x[idx];
            }
        }
    }
}

// ---------------------------------------------------------------------------
// MFMA flash attention, Q-tile 64 (grid 1536 = 6 blocks/CU), async swizzled
// staging for Q/K/V (GEMM-identical geometry, conflict-free frag reads),
// scale pre-folded into Q, wave-uniform mask fast path.
// Wave w owns queries w*16..w*16+15 (one m-tile).
// ---------------------------------------------------------------------------
__global__ __launch_bounds__(256) void attn_mfma_kernel(
    const unsigned short* __restrict__ q, const unsigned short* __restrict__ k,
    const unsigned short* __restrict__ vt, const int* __restrict__ mask,
    unsigned short* __restrict__ ctxb)
{
    __shared__ __align__(16) unsigned short Qs[64 * 64];
    __shared__ __align__(16) unsigned short Ks[64 * 64];
    __shared__ __align__(16) unsigned short Vs[64 * 64];   // V^T tile: [d][key]
    __shared__ __align__(16) unsigned short Ps[64 * PADP];
    __shared__ float maskF[64];
    __shared__ int cleanS;

    const int tid  = threadIdx.x;
    const int lane = tid & 63;
    const int w    = tid >> 6;
    const int quad = lane >> 4;
    const int l16  = lane & 15;
    const int q0   = blockIdx.x * 64;
    const int h    = blockIdx.y;
    const int b    = blockIdx.z;

    const unsigned short* qp  = q  + ((size_t)(b * NH + h) * SEQ + q0) * DHEAD;
    const unsigned short* kp  = k  + (size_t)(b * NH + h) * SEQ * DHEAD;
    const unsigned short* vtp = vt + (size_t)(b * NH + h) * DHEAD * SEQ;

    const int rloc = lane >> 3;               // 0..7 row-within-inst
    const int csw  = (lane & 7) ^ rloc;       // swizzled logical chunk
    const int p0   = (quad ^ (l16 & 7)) * 8;  // frag-read chunk pos (shorts)

    // stage Q tile (64x64) via async copies: 8 insts, 2 per wave
    #pragma unroll
    for (int ii = 0; ii < 2; ++ii) {
        const int inst = 2 * w + ii;
        async_copy16(qp + (size_t)(inst * 8 + rloc) * DHEAD + csw * 8, Qs + inst * 512);
    }
    __syncthreads();   // drains vmcnt -> Q landed

    bf16x8 aQ[2];
    #pragma unroll
    for (int ks = 0; ks < 2; ++ks)
        aQ[ks] = *(const bf16x8*)&Qs[(w * 16 + l16) * 64 + (p0 ^ (ks * 32))];

    bf16x8 ones;
    #pragma unroll
    for (int j = 0; j < 8; ++j) ones[j] = (short)0x3F80;   // bf16 1.0

    float m_st[4], l_st[4];
    #pragma unroll
    for (int r = 0; r < 4; ++r) { m_st[r] = -1e30f; l_st[r] = 0.f; }
    f32x4 o[4] = {};
    const f32x4 zf = {0.f, 0.f, 0.f, 0.f};

    for (int kt = 0; kt < SEQ; kt += 64) {
        __syncthreads();   // prior iter's Ks/Vs frag reads drained
        #pragma unroll
        for (int ii = 0; ii < 2; ++ii) {
            const int inst = 2 * w + ii;
            async_copy16(kp  + (size_t)(kt + inst * 8 + rloc) * DHEAD + csw * 8, Ks + inst * 512);
            async_copy16(vtp + (size_t)(inst * 8 + rloc) * SEQ + kt + csw * 8,   Vs + inst * 512);
        }
        if (tid < 64) {
            const bool pm = mask[b * SEQ + kt + tid] > 0;
            maskF[tid] = pm ? 0.f : -1e9f;
            unsigned long long bb = __ballot(pm);
            if (tid == 0) cleanS = (bb == 0xFFFFFFFFFFFFFFFFull) ? 1 : 0;
        }
        __syncthreads();   // K/V landed + mask flag visible

        // S = (Q*scale)·K^T   C-layout: row(query)=quad*4+r, col(key)=l16
        f32x4 s[4];
        #pragma unroll
        for (int ni = 0; ni < 4; ++ni) {
            bf16x8 bK0 = *(const bf16x8*)&Ks[(ni * 16 + l16) * 64 + p0];
            bf16x8 bK1 = *(const bf16x8*)&Ks[(ni * 16 + l16) * 64 + (p0 ^ 32)];
            f32x4 t0 = __builtin_amdgcn_mfma_f32_16x16x32_bf16(aQ[0], bK0, zf, 0, 0, 0);
            s[ni] = __builtin_amdgcn_mfma_f32_16x16x32_bf16(aQ[1], bK1, t0, 0, 0, 0);
        }
        if (cleanS == 0) {   // block-uniform slow path: apply key mask
            #pragma unroll
            for (int ni = 0; ni < 4; ++ni) {
                const float mk = maskF[ni * 16 + l16];
                #pragma unroll
                for (int r = 0; r < 4; ++r) s[ni][r] += mk;
            }
        }

        // per-row max (in-reg over ni, cross-lane over l16) + online rescale
        float alpha[4];
        #pragma unroll
        for (int r = 0; r < 4; ++r) {
            float mx = fmaxf(fmaxf(s[0][r], s[1][r]), fmaxf(s[2][r], s[3][r]));
            mx = fmaxf(mx, __shfl_xor(mx, 1));
            mx = fmaxf(mx, __shfl_xor(mx, 2));
            mx = fmaxf(mx, __shfl_xor(mx, 4));
            mx = fmaxf(mx, __shfl_xor(mx, 8));
            const float mo = m_st[r];
            const float mn = fmaxf(mo, mx);
            alpha[r] = __expf(mo - mn);
            m_st[r] = mn;
            l_st[r] *= alpha[r];
        }

        // P = exp(S - m) -> LDS (C-layout write, wave-private rows)
        #pragma unroll
        for (int ni = 0; ni < 4; ++ni)
            #pragma unroll
            for (int r = 0; r < 4; ++r)
                Ps[(w * 16 + quad * 4 + r) * PADP + ni * 16 + l16]
                    = f2bf(__expf(s[ni][r] - m_st[r]));
        #pragma unroll
        for (int ni = 0; ni < 4; ++ni)
            #pragma unroll
            for (int r = 0; r < 4; ++r)
                o[ni][r] *= alpha[r];

        // P back as A-frags (wave-internal LDS round trip)
        bf16x8 aP[2];
        #pragma unroll
        for (int ks = 0; ks < 2; ++ks)
            aP[ks] = *(const bf16x8*)&Ps[(w * 16 + l16) * PADP + quad * 8 + ks * 32];

        // row sums via ones-MFMA
        f32x4 t0 = __builtin_amdgcn_mfma_f32_16x16x32_bf16(aP[0], ones, zf, 0, 0, 0);
        f32x4 rs = __builtin_amdgcn_mfma_f32_16x16x32_bf16(aP[1], ones, t0, 0, 0, 0);

        // O += P · V   (B-frag: n=d (row of Vs), k=key, swizzled chunks)
        #pragma unroll
        for (int ni = 0; ni < 4; ++ni) {
            bf16x8 bV0 = *(const bf16x8*)&Vs[(ni * 16 + l16) * 64 + p0];
            bf16x8 bV1 = *(const bf16x8*)&Vs[(ni * 16 + l16) * 64 + (p0 ^ 32)];
            o[ni] = __builtin_amdgcn_mfma_f32_16x16x32_bf16(aP[0], bV0, o[ni], 0, 0, 0);
            o[ni] = __builtin_amdgcn_mfma_f32_16x16x32_bf16(aP[1], bV1, o[ni], 0, 0, 0);
        }
        #pragma unroll
        for (int r = 0; r < 4; ++r) l_st[r] += rs[r];
    }

    // epilogue: ctx[b, tok, h*64 + d] = O / l
    #pragma unroll
    for (int r = 0; r < 4; ++r) {
        const float inv = 1.f / l_st[r];
        const int tok = q0 + w * 16 + quad * 4 + r;
        #pragma unroll
        for (int ni = 0; ni < 4; ++ni)
            ctxb[(size_t)(b * SEQ + tok) * DMODEL + h * DHEAD + ni * 16 + l16]
                = f2bf(o[ni][r] * inv);
    }
}

// ---------------------------------------------------------------------------
// LayerNorm, in-place capable.
// ---------------------------------------------------------------------------
__global__ __launch_bounds__(256) void ln_kernel(
    const float* __restrict__ y, const float* __restrict__ gamma,
    const float* __restrict__ beta, float* __restrict__ out)
{
    const int t   = blockIdx.x;
    const int tid = threadIdx.x;
    const float* row = y + (size_t)t * DMODEL;

    float vals[3];
    float s = 0.f, s2 = 0.f;
    #pragma unroll
    for (int i = 0; i < 3; ++i) {
        float vv = row[tid + 256 * i];
        vals[i] = vv;
        s  += vv;
        s2 += vv * vv;
    }
    #pragma unroll
    for (int off = 32; off > 0; off >>= 1) {
        s  += __shfl_down(s,  off);
        s2 += __shfl_down(s2, off);
    }
    __shared__ float rbuf[8];
    int w = tid >> 6;
    if ((tid & 63) == 0) { rbuf[w] = s; rbuf[4 + w] = s2; }
    __syncthreads();
    float ts  = rbuf[0] + rbuf[1] + rbuf[2] + rbuf[3];
    float ts2 = rbuf[4] + rbuf[5] + rbuf[6] + rbuf[7];
    float mu  = ts * (1.f / DMODEL);
    float var = ts2 * (1.f / DMODEL) - mu * mu;
    float inv = rsqrtf(var + LN_EPS);
    #pragma unroll
    for (int i = 0; i < 3; ++i) {
        int c = tid + 256 * i;
        out[(size_t)t * DMODEL + c] = gamma[c] * (vals[i] - mu) * inv + beta[c];
    }
}

// ---------------------------------------------------------------------------
extern "C" void kernel_launch(void* const* d_in, const int* in_sizes, int n_in,
                              void* d_out, int out_size, void* d_ws, size_t ws_size,
                              hipStream_t stream) {
    const float* x     = (const float*)d_in[0];
    const int*   mask  = (const int*)  d_in[1];
    const float* Wq    = (const float*)d_in[2];
    const float* bq    = (const float*)d_in[3];
    const float* Wk    = (const float*)d_in[4];
    const float* bk    = (const float*)d_in[5];
    const float* Wv    = (const float*)d_in[6];
    const float* bv    = (const float*)d_in[7];
    const float* Wo    = (const float*)d_in[8];
    const float* bo    = (const float*)d_in[9];
    const float* gamma = (const float*)d_in[10];
    const float* beta  = (const float*)d_in[11];
    float* out = (float*)d_out;

    const size_t perTok = (size_t)NTOK * DMODEL;   // 6,291,456
    const size_t perW   = (size_t)DMODEL * DMODEL; //   589,824

    unsigned short* xb   = (unsigned short*)d_ws;
    unsigned short* wtq  = xb + perTok;
    unsigned short* wtk  = wtq + perW;
    unsigned short* wtv  = wtk + perW;
    unsigned short* wto  = wtv + perW;
    unsigned short* qb   = wto + perW;
    unsigned short* kb   = qb + perTok;
    unsigned short* vb   = kb + perTok;    // holds V^T: [B,H,DH,SEQ]
    unsigned short* ctxb = vb + perTok;
    float* y = out;   // O-proj output lives in d_out; LN runs in-place

    prep_kernel<<<6144 + 2304, 256, 0, stream>>>(
        x, Wq, Wk, Wv, Wo, xb, wtq, wtk, wtv, wto);

    mfma_gemm_qkv<<<dim3(NTOK / 128, DMODEL / 128, 3), 256, 0, stream>>>(
        xb, wtq, wtk, wtv, bq, bk, bv, qb, kb, vb);

    attn_mfma_kernel<<<dim3(SEQ / 64, NH, BATCH), 256, 0, stream>>>(qb, kb, vb, mask, ctxb);

    mfma_gemm_oproj<<<dim3(NTOK / 128, DMODEL / 128), 256, 0, stream>>>(
        ctxb, wto, bo, x, y);

    ln_kernel<<<NTOK, 256, 0, stream>>>(y, gamma, beta, out);
}

// Round 7
// 210.419 us; speedup vs baseline: 1.1712x; 1.0182x over previous
//
#include <hip/hip_runtime.h>
#include <math.h>

#define NH 12
#define DMODEL 768
#define DHEAD 64
#define BATCH 16
#define SEQ 512
#define NTOK (BATCH*SEQ)   // 8192
#define ATTN_SCALE 0.125f
#define LN_EPS 1e-3f
#define PADP 72            // padded LDS row length (shorts) for the P tile
#define KITERS (DMODEL/64) // 12 (BK=64)

typedef __attribute__((ext_vector_type(8))) short  bf16x8;
typedef __attribute__((ext_vector_type(8))) unsigned short ushort8;
typedef __attribute__((ext_vector_type(4))) float  f32x4;

__device__ __forceinline__ unsigned short f2bf(float f) {
    unsigned int u = __float_as_uint(f);
    unsigned int r = (u + 0x7fffu + ((u >> 16) & 1u)) >> 16;
    return (unsigned short)r;
}

__device__ __forceinline__ void async_copy16(const void* g, void* l) {
    __builtin_amdgcn_global_load_lds((const __attribute__((address_space(1))) void*)g,
                                     (__attribute__((address_space(3))) void*)l,
                                     16, 0, 0);
}

// ---------------------------------------------------------------------------
// Merged prep: blocks [0,6144) cast x fp32->bf16; blocks [6144,8448) build
// Wt[n][k] = bf16(W[k][n]) for the 4 weight matrices.
// ---------------------------------------------------------------------------
__global__ __launch_bounds__(256) void prep_kernel(
    const float* __restrict__ x,
    const float* __restrict__ Wq, const float* __restrict__ Wk,
    const float* __restrict__ Wv, const float* __restrict__ Wo,
    unsigned short* __restrict__ xb,
    unsigned short* __restrict__ tq, unsigned short* __restrict__ tk,
    unsigned short* __restrict__ tv, unsigned short* __restrict__ to_)
{
    __shared__ float tile[32][33];
    const int bid = blockIdx.x;
    const int tid = threadIdx.x;

    if (bid < 6144) {
        int i = (bid * 256 + tid) * 4;
        const float4 v = *(const float4*)(x + i);
        unsigned long long pack =
              (unsigned long long)f2bf(v.x)
            | ((unsigned long long)f2bf(v.y) << 16)
            | ((unsigned long long)f2bf(v.z) << 32)
            | ((unsigned long long)f2bf(v.w) << 48);
        *(unsigned long long*)(xb + i) = pack;
        return;
    }

    const int t   = bid - 6144;       // 0..2303
    const int zz  = t / 576;
    const int rem = t % 576;
    const float* W = (zz == 0) ? Wq : (zz == 1) ? Wk : (zz == 2) ? Wv : Wo;
    unsigned short* T = (zz == 0) ? tq : (zz == 1) ? tk : (zz == 2) ? tv : to_;

    const int bx = (rem / 24) * 32;   // k base
    const int by = (rem % 24) * 32;   // n base
    const int tx = tid & 31, ty = tid >> 5;   // ty 0..7

    #pragma unroll
    for (int i = 0; i < 32; i += 8)
        tile[ty + i][tx] = W[(size_t)(bx + ty + i) * DMODEL + by + tx];
    __syncthreads();
    #pragma unroll
    for (int i = 0; i < 32; i += 8)
        T[(size_t)(by + ty + i) * DMODEL + bx + tx] = f2bf(tile[tx][ty + i]);
}

// ---------------------------------------------------------------------------
// MFMA GEMM, single-buffered, BK=64, 128x128 tile, XOR-swizzled LDS (R5).
// QKV variant: bias; Q scaled by ATTN_SCALE (folded); Q,K scatter [B,H,L,DH];
// V scatter transposed [B,H,DH,SEQ].
// ---------------------------------------------------------------------------
__global__ __launch_bounds__(256, 4) void mfma_gemm_qkv(
    const unsigned short* __restrict__ xb,
    const unsigned short* __restrict__ wt0, const unsigned short* __restrict__ wt1,
    const unsigned short* __restrict__ wt2,
    const float* __restrict__ b0, const float* __restrict__ b1, const float* __restrict__ b2,
    unsigned short* __restrict__ o0, unsigned short* __restrict__ o1,
    unsigned short* __restrict__ o2)
{
    __shared__ __align__(16) unsigned short As[128 * 64];
    __shared__ __align__(16) unsigned short Bs[128 * 64];

    const int zz = blockIdx.z;
    const unsigned short* Wt = (zz == 0) ? wt0 : (zz == 1) ? wt1 : wt2;
    const float* bias        = (zz == 0) ? b0  : (zz == 1) ? b1  : b2;
    unsigned short* out      = (zz == 0) ? o0  : (zz == 1) ? o1  : o2;
    const float sc           = (zz == 0) ? ATTN_SCALE : 1.0f;

    const int tid  = threadIdx.x;
    const int lane = tid & 63;
    const int w    = tid >> 6;
    const int wm   = w >> 1, wn = w & 1;
    const int m0   = blockIdx.x * 128;
    const int n0   = blockIdx.y * 128;
    const int quad = lane >> 4;
    const int l16  = lane & 15;

    const int rloc = lane >> 3;               // 0..7 row-within-inst
    const int csw  = (lane & 7) ^ rloc;       // swizzled logical chunk
    int rowS[4];
    #pragma unroll
    for (int ii = 0; ii < 4; ++ii) rowS[ii] = (4 * w + ii) * 8 + rloc;

    const int p0 = ((quad ^ (l16 & 7)) * 8);

    f32x4 acc[4][4] = {};

    for (int kb = 0; kb < KITERS; ++kb) {
        const int k0 = kb * 64;
        #pragma unroll
        for (int ii = 0; ii < 4; ++ii) {
            async_copy16(xb + (size_t)(m0 + rowS[ii]) * DMODEL + k0 + csw * 8,
                         As + (4 * w + ii) * 512);
            async_copy16(Wt + (size_t)(n0 + rowS[ii]) * DMODEL + k0 + csw * 8,
                         Bs + (4 * w + ii) * 512);
        }
        __syncthreads();

        #pragma unroll
        for (int ks = 0; ks < 2; ++ks) {
            const int po = p0 ^ (ks * 32);
            bf16x8 a[4], b[4];
            #pragma unroll
            for (int mi = 0; mi < 4; ++mi)
                a[mi] = *(const bf16x8*)&As[(wm * 64 + mi * 16 + l16) * 64 + po];
            #pragma unroll
            for (int ni = 0; ni < 4; ++ni)
                b[ni] = *(const bf16x8*)&Bs[(wn * 64 + ni * 16 + l16) * 64 + po];
            #pragma unroll
            for (int mi = 0; mi < 4; ++mi)
                #pragma unroll
                for (int ni = 0; ni < 4; ++ni)
                    acc[mi][ni] = __builtin_amdgcn_mfma_f32_16x16x32_bf16(a[mi], b[ni], acc[mi][ni], 0, 0, 0);
        }
        __syncthreads();
    }

    if (zz == 2) {
        #pragma unroll
        for (int ni = 0; ni < 4; ++ni) {
            const int ncol = n0 + wn * 64 + ni * 16 + l16;
            const int h = ncol >> 6, dh = ncol & 63;
            const float bv = bias[ncol];
            #pragma unroll
            for (int mi = 0; mi < 4; ++mi) {
                const int mbase = m0 + wm * 64 + mi * 16 + quad * 4;
                const int bi = mbase >> 9, l = mbase & 511;
                unsigned long long pack = 0;
                #pragma unroll
                for (int r = 0; r < 4; ++r)
                    pack |= (unsigned long long)f2bf(acc[mi][ni][r] + bv) << (16 * r);
                *(unsigned long long*)(out + ((size_t)((bi * NH + h) * DHEAD + dh)) * SEQ + l) = pack;
            }
        }
    } else {
        #pragma unroll
        for (int ni = 0; ni < 4; ++ni) {
            const int ncol = n0 + wn * 64 + ni * 16 + l16;
            const int h = ncol >> 6, dh = ncol & 63;
            const float bv = bias[ncol];
            #pragma unroll
            for (int mi = 0; mi < 4; ++mi) {
                const int mbase = m0 + wm * 64 + mi * 16 + quad * 4;
                #pragma unroll
                for (int r = 0; r < 4; ++r) {
                    const int t = mbase + r;
                    const int bi = t >> 9, l = t & 511;
                    out[(size_t)((bi * NH + h) * SEQ + l) * DHEAD + dh] = f2bf((acc[mi][ni][r] + bv) * sc);
                }
            }
        }
    }
}

// O-proj variant: y = ctx @ Wo + bo + x (fp32 out), same swizzled BK=64 loop.
__global__ __launch_bounds__(256, 4) void mfma_gemm_oproj(
    const unsigned short* __restrict__ ctxb, const unsigned short* __restrict__ wto,
    const float* __restrict__ bo, const float* __restrict__ x,
    float* __restrict__ y)
{
    __shared__ __align__(16) unsigned short As[128 * 64];
    __shared__ __align__(16) unsigned short Bs[128 * 64];

    const int tid  = threadIdx.x;
    const int lane = tid & 63;
    const int w    = tid >> 6;
    const int wm   = w >> 1, wn = w & 1;
    const int m0   = blockIdx.x * 128;
    const int n0   = blockIdx.y * 128;
    const int quad = lane >> 4;
    const int l16  = lane & 15;

    const int rloc = lane >> 3;
    const int csw  = (lane & 7) ^ rloc;
    int rowS[4];
    #pragma unroll
    for (int ii = 0; ii < 4; ++ii) rowS[ii] = (4 * w + ii) * 8 + rloc;
    const int p0 = ((quad ^ (l16 & 7)) * 8);

    f32x4 acc[4][4] = {};

    for (int kb = 0; kb < KITERS; ++kb) {
        const int k0 = kb * 64;
        #pragma unroll
        for (int ii = 0; ii < 4; ++ii) {
            async_copy16(ctxb + (size_t)(m0 + rowS[ii]) * DMODEL + k0 + csw * 8,
                         As + (4 * w + ii) * 512);
            async_copy16(wto  + (size_t)(n0 + rowS[ii]) * DMODEL + k0 + csw * 8,
                         Bs + (4 * w + ii) * 512);
        }
        __syncthreads();

        #pragma unroll
        for (int ks = 0; ks < 2; ++ks) {
            const int po = p0 ^ (ks * 32);
            bf16x8 a[4], b[4];
            #pragma unroll
            for (int mi = 0; mi < 4; ++mi)
                a[mi] = *(const bf16x8*)&As[(wm * 64 + mi * 16 + l16) * 64 + po];
            #pragma unroll
            for (int ni = 0; ni < 4; ++ni)
                b[ni] = *(const bf16x8*)&Bs[(wn * 64 + ni * 16 + l16) * 64 + po];
            #pragma unroll
            for (int mi = 0; mi < 4; ++mi)
                #pragma unroll
                for (int ni = 0; ni < 4; ++ni)
                    acc[mi][ni] = __builtin_amdgcn_mfma_f32_16x16x32_bf16(a[mi], b[ni], acc[mi][ni], 0, 0, 0);
        }
        __syncthreads();
    }

    #pragma unroll
    for (int ni = 0; ni < 4; ++ni) {
        const int ncol = n0 + wn * 64 + ni * 16 + l16;
        const float bv = bo[ncol];
        #pragma unroll
        for (int mi = 0; mi < 4; ++mi) {
            const int mbase = m0 + wm * 64 + mi * 16 + quad * 4;
            #pragma unroll
            for (int r = 0; r < 4; ++r) {
                const size_t idx = (size_t)(mbase + r) * DMODEL + ncol;
                y[idx] = acc[mi][ni][r] + bv + x[idx];
            }
        }
    }
}

// ---------------------------------------------------------------------------
// MFMA flash attention v3.
//  - grid linearized: id = qt*192 + (b*NH+h); 192%8==0 so all 8 q-tiles of a
//    head share id%8 -> same XCD -> K/V L2 reuse (R6 FETCH was 104MB, 8x dup).
//  - K/V double-buffered, K-loop fully unrolled (static LDS addrs; avoids
//    R4's runtime-indexing VALU tax). One barrier per iter; prefetch issued
//    at iter start, drained by the end-of-iter barrier one compute phase later.
//  - mask hoisted to prologue (per-tile clean flags); P stored with trunc
//    (softmax self-normalizes over identical truncated P -> error cancels).
// ---------------------------------------------------------------------------
__global__ __launch_bounds__(256) void attn_mfma_kernel(
    const unsigned short* __restrict__ q, const unsigned short* __restrict__ k,
    const unsigned short* __restrict__ vt, const int* __restrict__ mask,
    unsigned short* __restrict__ ctxb)
{
    __shared__ __align__(16) unsigned short Qs[64 * 64];
    __shared__ __align__(16) unsigned short Ks[2][64 * 64];
    __shared__ __align__(16) unsigned short Vs[2][64 * 64];   // V^T: [d][key]
    __shared__ __align__(16) unsigned short Ps[64 * PADP];
    __shared__ float maskV[SEQ];
    __shared__ int   cleanS[8];

    const int tid  = threadIdx.x;
    const int lane = tid & 63;
    const int w    = tid >> 6;
    const int quad = lane >> 4;
    const int l16  = lane & 15;

    const int id = blockIdx.x;
    const int qt = id / (BATCH * NH);
    const int g  = id % (BATCH * NH);
    const int b  = g / NH, h = g % NH;
    const int q0 = qt * 64;

    const unsigned short* qp  = q  + ((size_t)(b * NH + h) * SEQ + q0) * DHEAD;
    const unsigned short* kp  = k  + (size_t)(b * NH + h) * SEQ * DHEAD;
    const unsigned short* vtp = vt + (size_t)(b * NH + h) * DHEAD * SEQ;

    const int rloc = lane >> 3;               // 0..7 row-within-inst
    const int csw  = (lane & 7) ^ rloc;       // swizzled logical chunk
    const int p0   = (quad ^ (l16 & 7)) * 8;  // frag-read chunk pos (shorts)

    // prologue: stage Q and K/V tile 0; build mask table + clean flags
    #pragma unroll
    for (int ii = 0; ii < 2; ++ii) {
        const int inst = 2 * w + ii;
        async_copy16(qp  + (size_t)(inst * 8 + rloc) * DHEAD + csw * 8, Qs + inst * 512);
        async_copy16(kp  + (size_t)(inst * 8 + rloc) * DHEAD + csw * 8, &Ks[0][inst * 512]);
        async_copy16(vtp + (size_t)(inst * 8 + rloc) * SEQ + csw * 8,   &Vs[0][inst * 512]);
    }
    #pragma unroll
    for (int j = 0; j < 2; ++j) {
        const int idx = tid + 256 * j;             // tile = idx>>6 = w + 4j
        const bool pm = mask[b * SEQ + idx] > 0;
        maskV[idx] = pm ? 0.f : -1e9f;
        const unsigned long long bb = __ballot(pm);
        if (lane == 0) cleanS[w + 4 * j] = (bb == ~0ull) ? 1 : 0;
    }
    __syncthreads();   // Q + tile0 landed, mask ready

    bf16x8 aQ[2];
    #pragma unroll
    for (int ks = 0; ks < 2; ++ks)
        aQ[ks] = *(const bf16x8*)&Qs[(w * 16 + l16) * 64 + (p0 ^ (ks * 32))];

    bf16x8 ones;
    #pragma unroll
    for (int j = 0; j < 8; ++j) ones[j] = (short)0x3F80;   // bf16 1.0

    float m_st[4], l_st[4];
    #pragma unroll
    for (int r = 0; r < 4; ++r) { m_st[r] = -1e30f; l_st[r] = 0.f; }
    f32x4 o[4] = {};
    const f32x4 zf = {0.f, 0.f, 0.f, 0.f};

    #pragma unroll
    for (int it = 0; it < 8; ++it) {
        const int cur = it & 1;
        if (it + 1 < 8) {      // prefetch next tile into the other buffer
            const int kt1 = (it + 1) * 64;
            #pragma unroll
            for (int ii = 0; ii < 2; ++ii) {
                const int inst = 2 * w + ii;
                async_copy16(kp  + (size_t)(kt1 + inst * 8 + rloc) * DHEAD + csw * 8,
                             &Ks[1 - cur][inst * 512]);
                async_copy16(vtp + (size_t)(inst * 8 + rloc) * SEQ + kt1 + csw * 8,
                             &Vs[1 - cur][inst * 512]);
            }
        }
        const int kt = it * 64;

        // S = (Q*scale)·K^T   C-layout: row(query)=quad*4+r, col(key)=l16
        f32x4 s[4];
        #pragma unroll
        for (int ni = 0; ni < 4; ++ni) {
            bf16x8 bK0 = *(const bf16x8*)&Ks[cur][(ni * 16 + l16) * 64 + p0];
            bf16x8 bK1 = *(const bf16x8*)&Ks[cur][(ni * 16 + l16) * 64 + (p0 ^ 32)];
            f32x4 t0 = __builtin_amdgcn_mfma_f32_16x16x32_bf16(aQ[0], bK0, zf, 0, 0, 0);
            s[ni] = __builtin_amdgcn_mfma_f32_16x16x32_bf16(aQ[1], bK1, t0, 0, 0, 0);
        }
        if (cleanS[it] == 0) {   // rare slow path: apply key mask
            #pragma unroll
            for (int ni = 0; ni < 4; ++ni) {
                const float mk = maskV[kt + ni * 16 + l16];
                #pragma unroll
                for (int r = 0; r < 4; ++r) s[ni][r] += mk;
            }
        }

        // per-row max + online rescale
        float alpha[4];
        #pragma unroll
        for (int r = 0; r < 4; ++r) {
            float mx = fmaxf(fmaxf(s[0][r], s[1][r]), fmaxf(s[2][r], s[3][r]));
            mx = fmaxf(mx, __shfl_xor(mx, 1));
            mx = fmaxf(mx, __shfl_xor(mx, 2));
            mx = fmaxf(mx, __shfl_xor(mx, 4));
            mx = fmaxf(mx, __shfl_xor(mx, 8));
            const float mo = m_st[r];
            const float mn = fmaxf(mo, mx);
            alpha[r] = __expf(mo - mn);
            m_st[r] = mn;
            l_st[r] *= alpha[r];
        }

        // P = exp(S - m) -> LDS (truncating cast; wave-private rows)
        #pragma unroll
        for (int ni = 0; ni < 4; ++ni)
            #pragma unroll
            for (int r = 0; r < 4; ++r)
                Ps[(w * 16 + quad * 4 + r) * PADP + ni * 16 + l16]
                    = (unsigned short)(__float_as_uint(__expf(s[ni][r] - m_st[r])) >> 16);
        #pragma unroll
        for (int ni = 0; ni < 4; ++ni)
            #pragma unroll
            for (int r = 0; r < 4; ++r)
                o[ni][r] *= alpha[r];

        // P back as A-frags (wave-internal LDS round trip)
        bf16x8 aP[2];
        #pragma unroll
        for (int ks = 0; ks < 2; ++ks)
            aP[ks] = *(const bf16x8*)&Ps[(w * 16 + l16) * PADP + quad * 8 + ks * 32];

        // row sums via ones-MFMA
        f32x4 t0 = __builtin_amdgcn_mfma_f32_16x16x32_bf16(aP[0], ones, zf, 0, 0, 0);
        f32x4 rs = __builtin_amdgcn_mfma_f32_16x16x32_bf16(aP[1], ones, t0, 0, 0, 0);

        // O += P · V
        #pragma unroll
        for (int ni = 0; ni < 4; ++ni) {
            bf16x8 bV0 = *(const bf16x8*)&Vs[cur][(ni * 16 + l16) * 64 + p0];
            bf16x8 bV1 = *(const bf16x8*)&Vs[cur][(ni * 16 + l16) * 64 + (p0 ^ 32)];
            o[ni] = __builtin_amdgcn_mfma_f32_16x16x32_bf16(aP[0], bV0, o[ni], 0, 0, 0);
            o[ni] = __builtin_amdgcn_mfma_f32_16x16x32_bf16(aP[1], bV1, o[ni], 0, 0, 0);
        }
        #pragma unroll
        for (int r = 0; r < 4; ++r) l_st[r] += rs[r];

        __syncthreads();   // all waves done with buf[cur]; prefetch drained
    }

    // epilogue: ctx[b, tok, h*64 + d] = O / l
    #pragma unroll
    for (int r = 0; r < 4; ++r) {
        const float inv = 1.f / l_st[r];
        const int tok = q0 + w * 16 + quad * 4 + r;
        #pragma unroll
        for (int ni = 0; ni < 4; ++ni)
            ctxb[(size_t)(b * SEQ + tok) * DMODEL + h * DHEAD + ni * 16 + l16]
                = f2bf(o[ni][r] * inv);
    }
}

// ---------------------------------------------------------------------------
// LayerNorm, in-place capable.
// ---------------------------------------------------------------------------
__global__ __launch_bounds__(256) void ln_kernel(
    const float* __restrict__ y, const float* __restrict__ gamma,
    const float* __restrict__ beta, float* __restrict__ out)
{
    const int t   = blockIdx.x;
    const int tid = threadIdx.x;
    const float* row = y + (size_t)t * DMODEL;

    float vals[3];
    float s = 0.f, s2 = 0.f;
    #pragma unroll
    for (int i = 0; i < 3; ++i) {
        float vv = row[tid + 256 * i];
        vals[i] = vv;
        s  += vv;
        s2 += vv * vv;
    }
    #pragma unroll
    for (int off = 32; off > 0; off >>= 1) {
        s  += __shfl_down(s,  off);
        s2 += __shfl_down(s2, off);
    }
    __shared__ float rbuf[8];
    int w = tid >> 6;
    if ((tid & 63) == 0) { rbuf[w] = s; rbuf[4 + w] = s2; }
    __syncthreads();
    float ts  = rbuf[0] + rbuf[1] + rbuf[2] + rbuf[3];
    float ts2 = rbuf[4] + rbuf[5] + rbuf[6] + rbuf[7];
    float mu  = ts * (1.f / DMODEL);
    float var = ts2 * (1.f / DMODEL) - mu * mu;
    float inv = rsqrtf(var + LN_EPS);
    #pragma unroll
    for (int i = 0; i < 3; ++i) {
        int c = tid + 256 * i;
        out[(size_t)t * DMODEL + c] = gamma[c] * (vals[i] - mu) * inv + beta[c];
    }
}

// ---------------------------------------------------------------------------
extern "C" void kernel_launch(void* const* d_in, const int* in_sizes, int n_in,
                              void* d_out, int out_size, void* d_ws, size_t ws_size,
                              hipStream_t stream) {
    const float* x     = (const float*)d_in[0];
    const int*   mask  = (const int*)  d_in[1];
    const float* Wq    = (const float*)d_in[2];
    const float* bq    = (const float*)d_in[3];
    const float* Wk    = (const float*)d_in[4];
    const float* bk    = (const float*)d_in[5];
    const float* Wv    = (const float*)d_in[6];
    const float* bv    = (const float*)d_in[7];
    const float* Wo    = (const float*)d_in[8];
    const float* bo    = (const float*)d_in[9];
    const float* gamma = (const float*)d_in[10];
    const float* beta  = (const float*)d_in[11];
    float* out = (float*)d_out;

    const size_t perTok = (size_t)NTOK * DMODEL;   // 6,291,456
    const size_t perW   = (size_t)DMODEL * DMODEL; //   589,824

    unsigned short* xb   = (unsigned short*)d_ws;
    unsigned short* wtq  = xb + perTok;
    unsigned short* wtk  = wtq + perW;
    unsigned short* wtv  = wtk + perW;
    unsigned short* wto  = wtv + perW;
    unsigned short* qb   = wto + perW;
    unsigned short* kb   = qb + perTok;
    unsigned short* vb   = kb + perTok;    // holds V^T: [B,H,DH,SEQ]
    unsigned short* ctxb = vb + perTok;
    float* y = out;   // O-proj output lives in d_out; LN runs in-place

    prep_kernel<<<6144 + 2304, 256, 0, stream>>>(
        x, Wq, Wk, Wv, Wo, xb, wtq, wtk, wtv, wto);

    mfma_gemm_qkv<<<dim3(NTOK / 128, DMODEL / 128, 3), 256, 0, stream>>>(
        xb, wtq, wtk, wtv, bq, bk, bv, qb, kb, vb);

    attn_mfma_kernel<<<dim3((SEQ / 64) * BATCH * NH), 256, 0, stream>>>(
        qb, kb, vb, mask, ctxb);

    mfma_gemm_oproj<<<dim3(NTOK / 128, DMODEL / 128), 256, 0, stream>>>(
        ctxb, wto, bo, x, y);

    ln_kernel<<<NTOK, 256, 0, stream>>>(y, gamma, beta, out);
}